// Round 1
// baseline (35.707 us; speedup 1.0000x reference)
//
#include <hip/hip_runtime.h>

// ---- problem constants (fixed by reference) ----
#define B_TOK   128
#define E_TOP   4
#define NEXP    32
#define KDIM    512
#define CDIM    1024
#define PAIRS   (B_TOK * E_TOP)   // 512 (token, expert) assignments
#define HALF_C  (CDIM / 2)        // 512 output channels per pair

#define ALPHA   1.702f
#define LIMIT   7.0f

// ---- tiling ----
#define CH      128               // channels per block
#define TT      16                // tokens per chunk
#define KT      32                // k-tile per stage (per k-half)
#define KHALF   (KDIM / 2)        // 256: each thread-half covers half of K
#define WST     (KT + 1)          // 33: padded w_lds row stride (floats)
#define XST     TT                // 16: xs row stride (floats)

// =====================================================================
// Kernel 1: bucket the 512 (b,e) assignments by expert id.
// lists[e*PAIRS + i] = pair index (b*E + e_slot); counts[e] = #assigned.
// Output values do not depend on intra-list order -> deterministic.
// =====================================================================
__global__ void bucket_kernel(const int* __restrict__ idx,
                              unsigned short* __restrict__ lists,
                              int* __restrict__ counts) {
    __shared__ int cnt[NEXP];
    const int t = threadIdx.x;           // 0..511
    if (t < NEXP) cnt[t] = 0;
    __syncthreads();
    const int e = idx[t];
    const int pos = atomicAdd(&cnt[e], 1);
    lists[e * PAIRS + pos] = (unsigned short)t;
    __syncthreads();
    if (t < NEXP) counts[t] = cnt[t];
}

// fused activation: glu channel g (even), linear channel l (odd)
__device__ __forceinline__ float glu_act(float g, float l) {
    g = fminf(g, LIMIT);
    l = fminf(fmaxf(l, -LIMIT), LIMIT);
    const float sg = 1.0f / (1.0f + __expf(-ALPHA * g));
    return (g * sg) * (l + 1.0f);
}

// =====================================================================
// Kernel 2: per (expert, channel-chunk, token-chunk) GEMM tile.
// block = 256 threads = 2 k-halves x 128 threads.
// Each 128-thread half: 32 channel-groups x 4 token-groups,
// thread tile = 4 tokens x 4 channels (16 fp32 accumulators).
// =====================================================================
__global__ __launch_bounds__(256, 2) void moe_mlp1_kernel(
    const float* __restrict__ x,      // [128, 512]
    const float* __restrict__ w,      // [32, 1024, 512]
    const float* __restrict__ bias,   // [32, 1024]
    const unsigned short* __restrict__ lists,
    const int* __restrict__ counts,
    float* __restrict__ out)          // [128, 4, 512] fp32
{
    __shared__ float xs[KDIM * XST];          // x transposed [k][t]   : 32 KB
    __shared__ float wsh[2 * CH * WST];       // per-half W tile [c][k]: 33.8 KB
                                              // (also reused as 8 KB reduce buf)

    const int tid   = threadIdx.x;
    const int e     = blockIdx.y;
    const int cBase = blockIdx.x * CH;
    const int T     = counts[e];

    const int kh   = tid >> 7;        // which k-half (0/1)
    const int tid2 = tid & 127;
    const int t0   = (tid2 & 3) * 4;  // token sub-tile base (0..12)
    const int c0   = (tid2 >> 2) * 4; // channel sub-tile base (0..124)
    const int kOff = kh * KHALF;

    for (int chunk = blockIdx.z; chunk * TT < T; chunk += gridDim.z) {
        const int tBase = chunk * TT;
        const int nT    = min(TT, T - tBase);

        __syncthreads();  // xs/wsh safe to overwrite (prev iter fully read)

        // ---- stage x chunk, transposed to [k][t] ----
        {
            const int tok = tid & 15;
            const int kq  = tid >> 4;            // 0..15
            const bool v  = (tok < nT);
            const int pairIdx = v ? (int)lists[e * PAIRS + tBase + tok] : 0;
            const int brow    = pairIdx >> 2;    // pair / E_TOP
            const float4* xrow = (const float4*)(x + (size_t)brow * KDIM);
            #pragma unroll
            for (int rep = 0; rep < 8; ++rep) {
                const int k = kq * 4 + rep * 64;
                float4 val = v ? xrow[k >> 2] : make_float4(0.f, 0.f, 0.f, 0.f);
                xs[(k + 0) * XST + tok] = val.x;
                xs[(k + 1) * XST + tok] = val.y;
                xs[(k + 2) * XST + tok] = val.z;
                xs[(k + 3) * XST + tok] = val.w;
            }
        }

        float acc[4][4];
        #pragma unroll
        for (int j = 0; j < 4; ++j)
            #pragma unroll
            for (int i = 0; i < 4; ++i) acc[j][i] = 0.f;

        // ---- K loop: stage W tile to LDS, outer-product FMAs ----
        const int k4     = tid2 & 7;   // float4 slot within k-tile
        const int ccBase = tid2 >> 3;  // 0..15
        float* const wbuf = &wsh[kh * CH * WST];

        for (int k0 = 0; k0 < KHALF; k0 += KT) {
            __syncthreads();  // prev tile consumed (and xs ready on 1st iter)
            #pragma unroll
            for (int p = 0; p < 8; ++p) {
                const int c = ccBase + p * 16;
                const float* wrow = w + ((size_t)e * CDIM + cBase + c) * KDIM
                                      + kOff + k0;
                const float4 val = *(const float4*)(wrow + k4 * 4);
                float* dst = wbuf + c * WST + k4 * 4;
                dst[0] = val.x; dst[1] = val.y; dst[2] = val.z; dst[3] = val.w;
            }
            __syncthreads();

            #pragma unroll 8
            for (int kk = 0; kk < KT; ++kk) {
                const float4 xv = *(const float4*)&xs[(kOff + k0 + kk) * XST + t0];
                const float xv4[4] = {xv.x, xv.y, xv.z, xv.w};
                float wv[4];
                #pragma unroll
                for (int i = 0; i < 4; ++i) wv[i] = wbuf[(c0 + i) * WST + kk];
                #pragma unroll
                for (int j = 0; j < 4; ++j)
                    #pragma unroll
                    for (int i = 0; i < 4; ++i)
                        acc[j][i] = fmaf(xv4[j], wv[i], acc[j][i]);
            }
        }

        // ---- combine the two k-halves through LDS ----
        __syncthreads();                      // all compute reads done
        if (kh == 1) {
            #pragma unroll
            for (int j = 0; j < 4; ++j) {
                float4 v = make_float4(acc[j][0], acc[j][1], acc[j][2], acc[j][3]);
                *(float4*)&wsh[(tid2 * 4 + j) * 4] = v;
            }
        }
        __syncthreads();
        if (kh == 0) {
            const float* bp = bias + (size_t)e * CDIM + cBase + c0;
            const float b0 = bp[0], b1 = bp[1], b2 = bp[2], b3 = bp[3];
            #pragma unroll
            for (int j = 0; j < 4; ++j) {
                const float4 v = *(const float4*)&wsh[(tid2 * 4 + j) * 4];
                const int tl = t0 + j;
                if (tl < nT) {
                    const int pairIdx = (int)lists[e * PAIRS + tBase + tl];
                    const float v0 = acc[j][0] + v.x + b0;
                    const float v1 = acc[j][1] + v.y + b1;
                    const float v2 = acc[j][2] + v.z + b2;
                    const float v3 = acc[j][3] + v.w + b3;
                    float* orow = out + (size_t)pairIdx * HALF_C + (cBase + c0) / 2;
                    orow[0] = glu_act(v0, v1);
                    orow[1] = glu_act(v2, v3);
                }
            }
        }
    }
}

extern "C" void kernel_launch(void* const* d_in, const int* in_sizes, int n_in,
                              void* d_out, int out_size, void* d_ws, size_t ws_size,
                              hipStream_t stream) {
    const float* x    = (const float*)d_in[0];   // normed_x [128,512]
    const int*   idx  = (const int*)d_in[1];     // expert_indices [128,4]
    const float* w    = (const float*)d_in[2];   // mlp1_weight [32,1024,512]
    const float* bias = (const float*)d_in[3];   // mlp1_bias [32,1024]
    float* out = (float*)d_out;                  // [128,4,512] fp32

    unsigned short* lists = (unsigned short*)d_ws;                  // 32 KB
    int* counts = (int*)((char*)d_ws + NEXP * PAIRS * sizeof(unsigned short));

    bucket_kernel<<<1, PAIRS, 0, stream>>>(idx, lists, counts);

    dim3 grid(CDIM / CH, NEXP, 2);   // (8, 32, 2) = 512 blocks
    moe_mlp1_kernel<<<grid, 256, 0, stream>>>(x, w, bias, lists, counts, out);
}